// Round 12
// baseline (121.269 us; speedup 1.0000x reference)
//
#include <hip/hip_runtime.h>
#include <hip/hip_fp16.h>

typedef __attribute__((ext_vector_type(8))) _Float16 f16x8;
typedef __attribute__((ext_vector_type(4))) float f32x4;
typedef __attribute__((ext_vector_type(2))) __fp16 fp16x2;

__device__ inline unsigned int pack_f16(float x, float y) {
    union { fp16x2 h; unsigned int u; } c;
    c.h = __builtin_amdgcn_cvt_pkrtz(x, y);
    return c.u;
}
__device__ inline float2 unpack_f16(unsigned int u) {
    union { unsigned int u32; __half2 h2; } c; c.u32 = u;
    return __half22float2(c.h2);
}

// ---------------------------------------------------------------------------
// Kernel 0 (grid 224): bid<128: transpose+cvt W -> WT16[u][d] fp16.
//                      bid 128..191: enc fp32 -> fp16.  192..223: dec -> fp16.
// ---------------------------------------------------------------------------
__global__ __launch_bounds__(256) void prep_w(
    const float* __restrict__ Wenc, const float* __restrict__ Wdec,
    const float* __restrict__ enc,  const float* __restrict__ dec,
    unsigned short* __restrict__ WeT, unsigned short* __restrict__ WdT,
    unsigned short* __restrict__ enc16, unsigned short* __restrict__ dec16)
{
    __shared__ float L[64][65];
    const int bid = blockIdx.x;
    const int t = threadIdx.x;
    if (bid >= 128) {                    // fp32 -> fp16 bulk convert
        const float* src; unsigned int* dst;
        if (bid < 192) { int blk = bid - 128; src = enc + (size_t)blk * 16384;
                         dst = (unsigned int*)enc16 + (size_t)blk * 8192; }
        else           { int blk = bid - 192; src = dec + (size_t)blk * 16384;
                         dst = (unsigned int*)dec16 + (size_t)blk * 8192; }
#pragma unroll 4
        for (int i = 0; i < 16; ++i) {
            int off = (i << 10) + (t << 2);
            float4 v = *(const float4*)(src + off);
            *(uint2*)(dst + (off >> 1)) =
                make_uint2(pack_f16(v.x, v.y), pack_f16(v.z, v.w));
        }
        return;
    }
    const float* W = (bid < 64) ? Wenc : Wdec;
    unsigned short* T = (bid < 64) ? WeT : WdT;
    const int tb = bid & 63;
    const int d0 = (tb >> 3) << 6, u0v = (tb & 7) << 6;
    {
        const int c4 = (t & 15) << 2;
#pragma unroll
        for (int i = 0; i < 4; ++i) {
            int row = (i << 4) + (t >> 4);
            float4 v = *(const float4*)&W[(size_t)(d0 + row) * 512 + u0v + c4];
            L[row][c4 + 0] = v.x;
            L[row][c4 + 1] = v.y;
            L[row][c4 + 2] = v.z;
            L[row][c4 + 3] = v.w;
        }
    }
    __syncthreads();
    const int u = t >> 2, dg = t & 3;
    unsigned int hw[8];
#pragma unroll
    for (int j = 0; j < 8; ++j) {
        float x0 = L[(dg << 4) + (j << 1) + 0][u];
        float x1 = L[(dg << 4) + (j << 1) + 1][u];
        hw[j] = pack_f16(x0, x1);
    }
    size_t ob = (size_t)(u0v + u) * 512 + d0 + (dg << 4);
    *(uint4*)&T[ob]     = make_uint4(hw[0], hw[1], hw[2], hw[3]);
    *(uint4*)&T[ob + 8] = make_uint4(hw[4], hw[5], hw[6], hw[7]);
}

// ---------------------------------------------------------------------------
// Kernel 1 (grid 1536 x 256 thr = 6144 waves = 24 waves/CU): fp16 MFMA
// projections, 16x16 tile PER WAVE (1 MFMA + 2x16B loads per k-step), no LDS,
// 4-deep register pipeline (~56 VGPR -> no spill under (256,6)).
//   bid<1024 : enc proj. Epilogue: EH = exp2((d_enc+b)*2log2e) fp16 u-packed.
//   bid>=1024: dec proj. Epilogue: Gq4[b][q>>2][u][q&3] = exp2((dd+b)*2log2e),
//              one float4 store per lane.
// ---------------------------------------------------------------------------
__global__ __launch_bounds__(256, 6) void proj_kernel(
    const unsigned short* __restrict__ enc16, const unsigned short* __restrict__ dec16,
    const unsigned short* __restrict__ WeT,   const unsigned short* __restrict__ WdT,
    const float* __restrict__ bias_enc, const float* __restrict__ bias_dec,
    unsigned short* __restrict__ EH,   // [B][128][256][4] fp16
    float* __restrict__ Gq4)           // [B][32][512][4] fp32
{
    const float Cs = 2.8853900817779268f;   // 2*log2(e)
    const int bid = blockIdx.x;
    const int t = threadIdx.x;
    const int lane = t & 63, wv = t >> 6;
    const int frow = lane & 15, quad = lane >> 4;
    const int ko = quad << 3;

    const bool is_enc = (bid < 1024);
    int u0, e0, q0, b;
    const unsigned short *pa, *pb;
    if (is_enc) {
        b = bid & 7;
        const int s = bid >> 3;             // 0..127
        const int ut = s >> 2;              // 0..31
        const int et = ((s & 3) << 2) + wv; // 0..15
        u0 = ut << 4; e0 = et << 4; q0 = 0;
        pa = WeT + (size_t)(u0 + frow) * 512 + ko;
        pb = enc16 + (size_t)((b << 8) + e0 + frow) * 512 + ko;
    } else {
        const int bid2 = bid - 1024;
        b = bid2 & 7;
        const int s = bid2 >> 3;            // 0..63
        const int qt = s >> 3;              // 0..7
        const int ut = ((s & 7) << 2) + wv; // 0..31
        q0 = qt << 4; u0 = ut << 4; e0 = 0;
        pa = dec16 + (size_t)((b << 7) + q0 + frow) * 512 + ko;
        pb = WdT + (size_t)(u0 + frow) * 512 + ko;
    }

    f16x8 sa[4], sb[4];
    auto LD = [&](int st, int k) {
        sa[st] = *(const f16x8*)(pa + k);
        sb[st] = *(const f16x8*)(pb + k);
    };
    f32x4 acc = {0.f, 0.f, 0.f, 0.f};
    LD(0, 0); LD(1, 32); LD(2, 64); LD(3, 96);
    for (int k0 = 0; k0 < 512; k0 += 128) {
#pragma unroll
        for (int st = 0; st < 4; ++st) {
            acc = __builtin_amdgcn_mfma_f32_16x16x32_f16(sa[st], sb[st], acc, 0, 0, 0);
            LD(st, (k0 + 128 + (st << 5)) & 511);   // wrapped tail reload harmless
        }
    }

    // epilogue (C/D: row m = quad*4+reg = A-row, col n = frow = B-row)
    if (is_enc) {
        const int ub = u0 + (quad << 2);         // + reg g = u
        const int e  = e0 + frow;
        float4 bi = *(const float4*)&bias_enc[ub];
        float E0 = __builtin_amdgcn_exp2f((acc[0] + bi.x) * Cs);
        float E1 = __builtin_amdgcn_exp2f((acc[1] + bi.y) * Cs);
        float E2 = __builtin_amdgcn_exp2f((acc[2] + bi.z) * Cs);
        float E3 = __builtin_amdgcn_exp2f((acc[3] + bi.w) * Cs);
        ((uint2*)EH)[(((size_t)(b << 7) + (ub >> 2)) << 8) + e] =
            make_uint2(pack_f16(E0, E1), pack_f16(E2, E3));
    } else {
        const int qb = q0 + (quad << 2);         // + reg g = q
        const int u  = u0 + frow;
        float bi = bias_dec[u];
        float G0 = __builtin_amdgcn_exp2f((acc[0] + bi) * Cs);
        float G1 = __builtin_amdgcn_exp2f((acc[1] + bi) * Cs);
        float G2 = __builtin_amdgcn_exp2f((acc[2] + bi) * Cs);
        float G3 = __builtin_amdgcn_exp2f((acc[3] + bi) * Cs);
        size_t base = (((size_t)(b << 5) + (qb >> 2)) << 11) + ((size_t)u << 2);
        *(float4*)&Gq4[base] = make_float4(G0, G1, G2, G3);
    }
}

// ---------------------------------------------------------------------------
// Kernel 2 (grid 256, 1024 thr, q=4/block): scores -> softmax -> context.
// Score loop: E fp16 8B vector load, 2-DEEP double buffer; G (q-packed, 64B)
// and Wscore (16B) via readfirstlane-pinned SCALAR loads, 1 group ahead.
// s = rcp(1 + E*G); logits = -2*sum (consts cancel in softmax).
// __launch_bounds__(1024,4): 128-reg cap, no spill.
// ---------------------------------------------------------------------------
__global__ __launch_bounds__(1024, 4) void attend_kernel(
    const unsigned short* __restrict__ enc16,  // [B,256,512] fp16
    const unsigned short* __restrict__ EH,     // [B][128][256][4] fp16
    const float* __restrict__ Gq4,             // [B][32][512][4] fp32
    const float* __restrict__ Wscore,          // [512]
    float* __restrict__ out)                   // [B, 128, 512]
{
    __shared__ float smem[8192];         // score accs 16 KB / ctx partials 32 KB
    __shared__ float wT[256][4];         // softmax weights [e][q]

    const float LOG2E = 1.4426950408889634f;

    const int bid = blockIdx.x;
    const int b = bid & 7;               // XCD-local batch
    const int qt = (bid >> 3) & 31;
    const int q0 = qt << 2;
    const int tid = threadIdx.x;
    const int wv = tid >> 6, lane = tid & 63;

    // ---------------- scores ----------------
    const int e  = ((wv & 3) << 6) + lane;
    const int uq = wv >> 2;
    const int u0 = __builtin_amdgcn_readfirstlane(uq << 7);   // SGPR-pinned

    const uint2* Ep = (const uint2*)EH + (((size_t)(b << 7) + (u0 >> 2)) << 8) + e;
    const float* Gq = Gq4 + (((size_t)(b << 5) + qt) << 11);  // [512][4]
    const float* Wp = Wscore + u0;

    float a0 = 0.f, a1 = 0.f, a2 = 0.f, a3 = 0.f;
    uint2 deA = Ep[0];
    uint2 deB = Ep[1 << 8];
    float4 g0 = *(const float4*)(Gq + ((u0 + 0) << 2));
    float4 g1 = *(const float4*)(Gq + ((u0 + 1) << 2));
    float4 g2 = *(const float4*)(Gq + ((u0 + 2) << 2));
    float4 g3 = *(const float4*)(Gq + ((u0 + 3) << 2));
    float4 w4 = *(const float4*)(Wp);

    auto PROC = [&](uint2 cde, float4 cg0, float4 cg1, float4 cg2, float4 cg3,
                    float4 cw) {
        float2 f01 = unpack_f16(cde.x);
        float2 f23 = unpack_f16(cde.y);
        float E;
        E = f01.x;
        a0 = fmaf(cw.x, __builtin_amdgcn_rcpf(fmaf(E, cg0.x, 1.f)), a0);
        a1 = fmaf(cw.x, __builtin_amdgcn_rcpf(fmaf(E, cg0.y, 1.f)), a1);
        a2 = fmaf(cw.x, __builtin_amdgcn_rcpf(fmaf(E, cg0.z, 1.f)), a2);
        a3 = fmaf(cw.x, __builtin_amdgcn_rcpf(fmaf(E, cg0.w, 1.f)), a3);
        E = f01.y;
        a0 = fmaf(cw.y, __builtin_amdgcn_rcpf(fmaf(E, cg1.x, 1.f)), a0);
        a1 = fmaf(cw.y, __builtin_amdgcn_rcpf(fmaf(E, cg1.y, 1.f)), a1);
        a2 = fmaf(cw.y, __builtin_amdgcn_rcpf(fmaf(E, cg1.z, 1.f)), a2);
        a3 = fmaf(cw.y, __builtin_amdgcn_rcpf(fmaf(E, cg1.w, 1.f)), a3);
        E = f23.x;
        a0 = fmaf(cw.z, __builtin_amdgcn_rcpf(fmaf(E, cg2.x, 1.f)), a0);
        a1 = fmaf(cw.z, __builtin_amdgcn_rcpf(fmaf(E, cg2.y, 1.f)), a1);
        a2 = fmaf(cw.z, __builtin_amdgcn_rcpf(fmaf(E, cg2.z, 1.f)), a2);
        a3 = fmaf(cw.z, __builtin_amdgcn_rcpf(fmaf(E, cg2.w, 1.f)), a3);
        E = f23.y;
        a0 = fmaf(cw.w, __builtin_amdgcn_rcpf(fmaf(E, cg3.x, 1.f)), a0);
        a1 = fmaf(cw.w, __builtin_amdgcn_rcpf(fmaf(E, cg3.y, 1.f)), a1);
        a2 = fmaf(cw.w, __builtin_amdgcn_rcpf(fmaf(E, cg3.z, 1.f)), a2);
        a3 = fmaf(cw.w, __builtin_amdgcn_rcpf(fmaf(E, cg3.w, 1.f)), a3);
    };

    for (int g = 0; g < 32; g += 2) {
        // even group g: E from deA, G/w current
        uint2 cde = deA;
        float4 cg0 = g0, cg1 = g1, cg2 = g2, cg3 = g3, cw = w4;
        deA = Ep[(size_t)((g + 2) & 31) << 8];
        {   // load G/w for group g+1
            int un = u0 + ((g + 1) << 2);
            g0 = *(const float4*)(Gq + ((un + 0) << 2));
            g1 = *(const float4*)(Gq + ((un + 1) << 2));
            g2 = *(const float4*)(Gq + ((un + 2) << 2));
            g3 = *(const float4*)(Gq + ((un + 3) << 2));
            w4 = *(const float4*)(Wp + ((g + 1) << 2));
        }
        PROC(cde, cg0, cg1, cg2, cg3, cw);

        // odd group g+1: E from deB, G/w current
        cde = deB;
        cg0 = g0; cg1 = g1; cg2 = g2; cg3 = g3; cw = w4;
        deB = Ep[(size_t)((g + 3) & 31) << 8];
        if (g < 30) {   // load G/w for group g+2
            int un = u0 + ((g + 2) << 2);
            g0 = *(const float4*)(Gq + ((un + 0) << 2));
            g1 = *(const float4*)(Gq + ((un + 1) << 2));
            g2 = *(const float4*)(Gq + ((un + 2) << 2));
            g3 = *(const float4*)(Gq + ((un + 3) << 2));
            w4 = *(const float4*)(Wp + ((g + 2) << 2));
        }
        PROC(cde, cg0, cg1, cg2, cg3, cw);
    }
    smem[((uq << 2) + 0) * 256 + e] = a0;
    smem[((uq << 2) + 1) * 256 + e] = a1;
    smem[((uq << 2) + 2) * 256 + e] = a2;
    smem[((uq << 2) + 3) * 256 + e] = a3;
    __syncthreads();

    // ---------------- softmax over e per q ----------------
    if (wv < 4) {
        const int q = wv;
        float l[4];
        float m = -1e30f;
#pragma unroll
        for (int i = 0; i < 4; ++i) {
            int ee = lane + (i << 6);
            float a = smem[(0 + q) * 256 + ee] + smem[(4 + q) * 256 + ee] +
                      smem[(8 + q) * 256 + ee] + smem[(12 + q) * 256 + ee];
            l[i] = -2.f * a;
            m = fmaxf(m, l[i]);
        }
#pragma unroll
        for (int mk = 32; mk >= 1; mk >>= 1) m = fmaxf(m, __shfl_xor(m, mk, 64));
        float p[4];
        float ssum = 0.f;
#pragma unroll
        for (int i = 0; i < 4; ++i) {
            p[i] = __builtin_amdgcn_exp2f((l[i] - m) * LOG2E);
            ssum += p[i];
        }
#pragma unroll
        for (int mk = 32; mk >= 1; mk >>= 1) ssum += __shfl_xor(ssum, mk, 64);
        float inv = __builtin_amdgcn_rcpf(ssum);
#pragma unroll
        for (int i = 0; i < 4; ++i) wT[lane + (i << 6)][q] = p[i] * inv;
    }
    __syncthreads();

    // ---------------- context (fp16 enc, 1x read, LDS reduce) ----------------
    {
        const int dp = tid & 255;                // d-pair index
        float p0x = 0.f, p0y = 0.f, p1x = 0.f, p1y = 0.f;
        float p2x = 0.f, p2y = 0.f, p3x = 0.f, p3y = 0.f;
        const unsigned int* ep = (const unsigned int*)enc16 +
                                 (((size_t)(b << 8) + (uq << 6)) << 8) + dp;
#pragma unroll 4
        for (int ee = 0; ee < 64; ++ee) {
            float2 x = unpack_f16(ep[(size_t)ee << 8]);
            float4 w = *(const float4*)&wT[(uq << 6) + ee][0];   // wave-uniform
            p0x = fmaf(w.x, x.x, p0x); p0y = fmaf(w.x, x.y, p0y);
            p1x = fmaf(w.y, x.x, p1x); p1y = fmaf(w.y, x.y, p1y);
            p2x = fmaf(w.z, x.x, p2x); p2y = fmaf(w.z, x.y, p2y);
            p3x = fmaf(w.w, x.x, p3x); p3y = fmaf(w.w, x.y, p3y);
        }
        float2* sc = (float2*)smem;              // [16][256] float2 = 32 KB
        sc[((uq << 2) + 0) * 256 + dp] = make_float2(p0x, p0y);
        sc[((uq << 2) + 1) * 256 + dp] = make_float2(p1x, p1y);
        sc[((uq << 2) + 2) * 256 + dp] = make_float2(p2x, p2y);
        sc[((uq << 2) + 3) * 256 + dp] = make_float2(p3x, p3y);
        __syncthreads();
        const int q = tid >> 8;                  // 0..3
        float2 s0 = sc[(0 + q) * 256 + dp];
        float2 s1 = sc[(4 + q) * 256 + dp];
        float2 s2 = sc[(8 + q) * 256 + dp];
        float2 s3 = sc[(12 + q) * 256 + dp];
        float2 o = make_float2(s0.x + s1.x + s2.x + s3.x,
                               s0.y + s1.y + s2.y + s3.y);
        *(float2*)&out[(size_t)((b << 7) + q0 + q) * 512 + (dp << 1)] = o;
    }
}

// ---------------------------------------------------------------------------
extern "C" void kernel_launch(void* const* d_in, const int* in_sizes, int n_in,
                              void* d_out, int out_size, void* d_ws, size_t ws_size,
                              hipStream_t stream) {
    const float* enc      = (const float*)d_in[0];
    const float* dec      = (const float*)d_in[1];
    const float* Wenc     = (const float*)d_in[2];
    const float* Wdec     = (const float*)d_in[3];
    const float* Wscore   = (const float*)d_in[4];
    const float* bias_enc = (const float*)d_in[5];
    const float* bias_dec = (const float*)d_in[6];
    // d_in[7] = bias_score: constant shift, cancelled by softmax.
    float* out = (float*)d_out;

    float* ws = (float*)d_ws;
    unsigned short* EH  = (unsigned short*)ws;             // 2 MB  (1M fp16)
    float* Gq4          = ws + 524288;                     // 2 MB  (512K fp32)
    unsigned short* WeT = (unsigned short*)(ws + 1048576); // 512 KB
    unsigned short* WdT = WeT + 262144;                    // 512 KB
    unsigned short* enc16 = WdT + 262144;                  // 2 MB
    unsigned short* dec16 = enc16 + 1048576;               // 1 MB   (total 8 MB)

    prep_w<<<224, 256, 0, stream>>>(Wenc, Wdec, enc, dec, WeT, WdT, enc16, dec16);
    proj_kernel<<<1536, 256, 0, stream>>>(enc16, dec16, WeT, WdT,
                                          bias_enc, bias_dec, EH, Gq4);
    attend_kernel<<<256, 1024, 0, stream>>>(enc16, EH, Gq4, Wscore, out);
}

// Round 13
// 114.362 us; speedup vs baseline: 1.0604x; 1.0604x over previous
//
#include <hip/hip_runtime.h>
#include <hip/hip_fp16.h>

typedef __attribute__((ext_vector_type(8))) _Float16 f16x8;
typedef __attribute__((ext_vector_type(4))) float f32x4;
typedef __attribute__((ext_vector_type(2))) __fp16 fp16x2;

__device__ inline unsigned int pack_f16(float x, float y) {
    union { fp16x2 h; unsigned int u; } c;
    c.h = __builtin_amdgcn_cvt_pkrtz(x, y);
    return c.u;
}
__device__ inline float2 unpack_f16(unsigned int u) {
    union { unsigned int u32; __half2 h2; } c; c.u32 = u;
    return __half22float2(c.h2);
}

// ---------------------------------------------------------------------------
// Kernel 0 (grid 224): bid<128: transpose+cvt W -> WT16[u][d] fp16.
//                      bid 128..191: enc fp32 -> fp16.  192..223: dec -> fp16.
// ---------------------------------------------------------------------------
__global__ __launch_bounds__(256) void prep_w(
    const float* __restrict__ Wenc, const float* __restrict__ Wdec,
    const float* __restrict__ enc,  const float* __restrict__ dec,
    unsigned short* __restrict__ WeT, unsigned short* __restrict__ WdT,
    unsigned short* __restrict__ enc16, unsigned short* __restrict__ dec16)
{
    __shared__ float L[64][65];
    const int bid = blockIdx.x;
    const int t = threadIdx.x;
    if (bid >= 128) {                    // fp32 -> fp16 bulk convert
        const float* src; unsigned int* dst;
        if (bid < 192) { int blk = bid - 128; src = enc + (size_t)blk * 16384;
                         dst = (unsigned int*)enc16 + (size_t)blk * 8192; }
        else           { int blk = bid - 192; src = dec + (size_t)blk * 16384;
                         dst = (unsigned int*)dec16 + (size_t)blk * 8192; }
#pragma unroll 4
        for (int i = 0; i < 16; ++i) {
            int off = (i << 10) + (t << 2);
            float4 v = *(const float4*)(src + off);
            *(uint2*)(dst + (off >> 1)) =
                make_uint2(pack_f16(v.x, v.y), pack_f16(v.z, v.w));
        }
        return;
    }
    const float* W = (bid < 64) ? Wenc : Wdec;
    unsigned short* T = (bid < 64) ? WeT : WdT;
    const int tb = bid & 63;
    const int d0 = (tb >> 3) << 6, u0v = (tb & 7) << 6;
    {
        const int c4 = (t & 15) << 2;
#pragma unroll
        for (int i = 0; i < 4; ++i) {
            int row = (i << 4) + (t >> 4);
            float4 v = *(const float4*)&W[(size_t)(d0 + row) * 512 + u0v + c4];
            L[row][c4 + 0] = v.x;
            L[row][c4 + 1] = v.y;
            L[row][c4 + 2] = v.z;
            L[row][c4 + 3] = v.w;
        }
    }
    __syncthreads();
    const int u = t >> 2, dg = t & 3;
    unsigned int hw[8];
#pragma unroll
    for (int j = 0; j < 8; ++j) {
        float x0 = L[(dg << 4) + (j << 1) + 0][u];
        float x1 = L[(dg << 4) + (j << 1) + 1][u];
        hw[j] = pack_f16(x0, x1);
    }
    size_t ob = (size_t)(u0v + u) * 512 + d0 + (dg << 4);
    *(uint4*)&T[ob]     = make_uint4(hw[0], hw[1], hw[2], hw[3]);
    *(uint4*)&T[ob + 8] = make_uint4(hw[4], hw[5], hw[6], hw[7]);
}

// ---------------------------------------------------------------------------
// Kernel 1 (grid 768, 128 thr = 2 waves): fp16 MFMA projections, no LDS,
// 4-deep register pipeline (64 stage VGPRs -> no spill under (128,1)).
// EXACT R11 version (32x32 tile/wave = 64 B/output traffic optimum).
//   bid<512 : enc proj, rows=u cols=e. Epilogue: EH = exp2((d_enc+b)*2log2e)
//             fp16, u-packed-by-4.
//   bid>=512: dec proj, rows=q cols=u. Epilogue:
//             Gq4[b][q>>2][u][q&3] = exp2((dd+b)*2log2e) fp32 (q-packed).
// ---------------------------------------------------------------------------
__global__ __launch_bounds__(128, 1) void proj_kernel(
    const unsigned short* __restrict__ enc16, const unsigned short* __restrict__ dec16,
    const unsigned short* __restrict__ WeT,   const unsigned short* __restrict__ WdT,
    const float* __restrict__ bias_enc, const float* __restrict__ bias_dec,
    unsigned short* __restrict__ EH,   // [B][128][256][4] fp16
    float* __restrict__ Gq4)           // [B][32][512][4] fp32
{
    const float Cs = 2.8853900817779268f;   // 2*log2(e)
    const int bid = blockIdx.x;
    const int t = threadIdx.x;
    const int lane = t & 63, wr = t >> 6;    // wr: 32-row half of 64-row tile
    const int frow = lane & 15, quad = lane >> 4;
    const int ko = quad << 3;

    const unsigned short *pa0, *pa1, *pb0, *pb1;
    if (bid < 512) {
        const int b = bid & 7, s = bid >> 3;
        const int u0 = ((s & 7) << 6) + (wr << 5);   // 8 u-tiles of 64
        const int e0 = (s >> 3) << 5;                // 8 e-tiles of 32
        pa0 = WeT + (size_t)(u0 + frow) * 512 + ko;
        pa1 = pa0 + 16 * 512;
        pb0 = enc16 + (size_t)((b << 8) + e0 + frow) * 512 + ko;
        pb1 = pb0 + 16 * 512;
    } else {
        const int s = bid - 512;
        const int b = s & 7, s2 = s >> 3;
        const int q0 = ((s2 >> 4) << 6) + (wr << 5); // 2 q-tiles of 64
        const int u0 = (s2 & 15) << 5;               // 16 u-tiles of 32
        pa0 = dec16 + (size_t)((b << 7) + q0 + frow) * 512 + ko;
        pa1 = pa0 + 16 * 512;
        pb0 = WdT + (size_t)(u0 + frow) * 512 + ko;
        pb1 = pb0 + 16 * 512;
    }

    f16x8 sa0[4], sa1[4], sb0[4], sb1[4];
    auto LD = [&](int st, int k) {
        sa0[st] = *(const f16x8*)(pa0 + k);
        sa1[st] = *(const f16x8*)(pa1 + k);
        sb0[st] = *(const f16x8*)(pb0 + k);
        sb1[st] = *(const f16x8*)(pb1 + k);
    };
    f32x4 acc[2][2] = {{{0.f,0.f,0.f,0.f},{0.f,0.f,0.f,0.f}},
                       {{0.f,0.f,0.f,0.f},{0.f,0.f,0.f,0.f}}};
    LD(0, 0); LD(1, 32); LD(2, 64); LD(3, 96);
    for (int k0 = 0; k0 < 512; k0 += 128) {
#pragma unroll
        for (int st = 0; st < 4; ++st) {
            acc[0][0] = __builtin_amdgcn_mfma_f32_16x16x32_f16(sa0[st], sb0[st], acc[0][0], 0, 0, 0);
            acc[0][1] = __builtin_amdgcn_mfma_f32_16x16x32_f16(sa0[st], sb1[st], acc[0][1], 0, 0, 0);
            acc[1][0] = __builtin_amdgcn_mfma_f32_16x16x32_f16(sa1[st], sb0[st], acc[1][0], 0, 0, 0);
            acc[1][1] = __builtin_amdgcn_mfma_f32_16x16x32_f16(sa1[st], sb1[st], acc[1][1], 0, 0, 0);
            LD(st, (k0 + 128 + (st << 5)) & 511);   // wrapped tail reload harmless
        }
    }

    // epilogue (C/D: col = lane&15 -> B-row, row = quad*4 + reg -> A-row)
    if (bid < 512) {
        const int b = bid & 7, s = bid >> 3;
        const int u0 = ((s & 7) << 6) + (wr << 5);
        const int e0 = (s >> 3) << 5;
#pragma unroll
        for (int fm = 0; fm < 2; ++fm)
#pragma unroll
            for (int fn = 0; fn < 2; ++fn) {
                int ub = u0 + (fm << 4) + (quad << 2);
                int e  = e0 + (fn << 4) + frow;
                float4 bi = *(const float4*)&bias_enc[ub];
                float E0 = __builtin_amdgcn_exp2f((acc[fm][fn][0] + bi.x) * Cs);
                float E1 = __builtin_amdgcn_exp2f((acc[fm][fn][1] + bi.y) * Cs);
                float E2 = __builtin_amdgcn_exp2f((acc[fm][fn][2] + bi.z) * Cs);
                float E3 = __builtin_amdgcn_exp2f((acc[fm][fn][3] + bi.w) * Cs);
                ((uint2*)EH)[(((size_t)(b << 7) + (ub >> 2)) << 8) + e] =
                    make_uint2(pack_f16(E0, E1), pack_f16(E2, E3));
            }
    } else {
        const int s = bid - 512;
        const int b = s & 7, s2 = s >> 3;
        const int q0 = ((s2 >> 4) << 6) + (wr << 5);
        const int u0 = (s2 & 15) << 5;
#pragma unroll
        for (int fm = 0; fm < 2; ++fm)
#pragma unroll
            for (int fn = 0; fn < 2; ++fn) {
                int qb = q0 + (fm << 4) + (quad << 2);   // multiple of 4
                int u  = u0 + (fn << 4) + frow;
                float bi = bias_dec[u];
                size_t base = (((size_t)(b << 5) + (qb >> 2)) << 11) + (u << 2);
#pragma unroll
                for (int g = 0; g < 4; ++g)
                    Gq4[base + g] =
                        __builtin_amdgcn_exp2f((acc[fm][fn][g] + bi) * Cs);
            }
    }
}

// ---------------------------------------------------------------------------
// Kernel 2 (grid 256, 1024 thr, q=4/block): scores -> softmax -> context.
// Score loop FULLY UNROLLED: G/w addresses become SGPR-base + immediate
// offsets -> compiler batches s_load_dwordx4 far ahead (kills the ~130
// cyc/group SMEM stall); E loads scheduler-pipelined under 128-VGPR cap.
// s = rcp(1 + E*G); logits = -2*sum (consts cancel in softmax).
// ---------------------------------------------------------------------------
__global__ __launch_bounds__(1024, 4) void attend_kernel(
    const unsigned short* __restrict__ enc16,  // [B,256,512] fp16
    const unsigned short* __restrict__ EH,     // [B][128][256][4] fp16
    const float* __restrict__ Gq4,             // [B][32][512][4] fp32
    const float* __restrict__ Wscore,          // [512]
    float* __restrict__ out)                   // [B, 128, 512]
{
    __shared__ float smem[8192];         // score accs 16 KB / ctx partials 32 KB
    __shared__ float wT[256][4];         // softmax weights [e][q]

    const float LOG2E = 1.4426950408889634f;

    const int bid = blockIdx.x;
    const int b = bid & 7;               // XCD-local batch
    const int qt = (bid >> 3) & 31;
    const int q0 = qt << 2;
    const int tid = threadIdx.x;
    const int wv = tid >> 6, lane = tid & 63;

    // ---------------- scores ----------------
    const int e  = ((wv & 3) << 6) + lane;
    const int uq = wv >> 2;
    const int u0 = __builtin_amdgcn_readfirstlane(uq << 7);   // SGPR-pinned

    const uint2* Ep = (const uint2*)EH + (((size_t)(b << 7) + (u0 >> 2)) << 8) + e;
    const float* Gq = Gq4 + (((size_t)(b << 5) + qt) << 11) + ((size_t)u0 << 2);
    const float* Wp = Wscore + u0;

    float a0 = 0.f, a1 = 0.f, a2 = 0.f, a3 = 0.f;
#pragma unroll
    for (int g = 0; g < 32; ++g) {
        uint2 cde = Ep[(size_t)g << 8];
        const float* gp = Gq + (g << 4);            // 4 u x 4 q floats
        float4 cg0 = *(const float4*)(gp);
        float4 cg1 = *(const float4*)(gp + 4);
        float4 cg2 = *(const float4*)(gp + 8);
        float4 cg3 = *(const float4*)(gp + 12);
        float4 cw  = *(const float4*)(Wp + (g << 2));
        float2 f01 = unpack_f16(cde.x);
        float2 f23 = unpack_f16(cde.y);
        float E;
        E = f01.x;
        a0 = fmaf(cw.x, __builtin_amdgcn_rcpf(fmaf(E, cg0.x, 1.f)), a0);
        a1 = fmaf(cw.x, __builtin_amdgcn_rcpf(fmaf(E, cg0.y, 1.f)), a1);
        a2 = fmaf(cw.x, __builtin_amdgcn_rcpf(fmaf(E, cg0.z, 1.f)), a2);
        a3 = fmaf(cw.x, __builtin_amdgcn_rcpf(fmaf(E, cg0.w, 1.f)), a3);
        E = f01.y;
        a0 = fmaf(cw.y, __builtin_amdgcn_rcpf(fmaf(E, cg1.x, 1.f)), a0);
        a1 = fmaf(cw.y, __builtin_amdgcn_rcpf(fmaf(E, cg1.y, 1.f)), a1);
        a2 = fmaf(cw.y, __builtin_amdgcn_rcpf(fmaf(E, cg1.z, 1.f)), a2);
        a3 = fmaf(cw.y, __builtin_amdgcn_rcpf(fmaf(E, cg1.w, 1.f)), a3);
        E = f23.x;
        a0 = fmaf(cw.z, __builtin_amdgcn_rcpf(fmaf(E, cg2.x, 1.f)), a0);
        a1 = fmaf(cw.z, __builtin_amdgcn_rcpf(fmaf(E, cg2.y, 1.f)), a1);
        a2 = fmaf(cw.z, __builtin_amdgcn_rcpf(fmaf(E, cg2.z, 1.f)), a2);
        a3 = fmaf(cw.z, __builtin_amdgcn_rcpf(fmaf(E, cg2.w, 1.f)), a3);
        E = f23.y;
        a0 = fmaf(cw.w, __builtin_amdgcn_rcpf(fmaf(E, cg3.x, 1.f)), a0);
        a1 = fmaf(cw.w, __builtin_amdgcn_rcpf(fmaf(E, cg3.y, 1.f)), a1);
        a2 = fmaf(cw.w, __builtin_amdgcn_rcpf(fmaf(E, cg3.z, 1.f)), a2);
        a3 = fmaf(cw.w, __builtin_amdgcn_rcpf(fmaf(E, cg3.w, 1.f)), a3);
    }
    smem[((uq << 2) + 0) * 256 + e] = a0;
    smem[((uq << 2) + 1) * 256 + e] = a1;
    smem[((uq << 2) + 2) * 256 + e] = a2;
    smem[((uq << 2) + 3) * 256 + e] = a3;
    __syncthreads();

    // ---------------- softmax over e per q ----------------
    if (wv < 4) {
        const int q = wv;
        float l[4];
        float m = -1e30f;
#pragma unroll
        for (int i = 0; i < 4; ++i) {
            int ee = lane + (i << 6);
            float a = smem[(0 + q) * 256 + ee] + smem[(4 + q) * 256 + ee] +
                      smem[(8 + q) * 256 + ee] + smem[(12 + q) * 256 + ee];
            l[i] = -2.f * a;
            m = fmaxf(m, l[i]);
        }
#pragma unroll
        for (int mk = 32; mk >= 1; mk >>= 1) m = fmaxf(m, __shfl_xor(m, mk, 64));
        float p[4];
        float ssum = 0.f;
#pragma unroll
        for (int i = 0; i < 4; ++i) {
            p[i] = __builtin_amdgcn_exp2f((l[i] - m) * LOG2E);
            ssum += p[i];
        }
#pragma unroll
        for (int mk = 32; mk >= 1; mk >>= 1) ssum += __shfl_xor(ssum, mk, 64);
        float inv = __builtin_amdgcn_rcpf(ssum);
#pragma unroll
        for (int i = 0; i < 4; ++i) wT[lane + (i << 6)][q] = p[i] * inv;
    }
    __syncthreads();

    // ---------------- context (fp16 enc, 1x read, LDS reduce) ----------------
    {
        const int dp = tid & 255;                // d-pair index
        float p0x = 0.f, p0y = 0.f, p1x = 0.f, p1y = 0.f;
        float p2x = 0.f, p2y = 0.f, p3x = 0.f, p3y = 0.f;
        const unsigned int* ep = (const unsigned int*)enc16 +
                                 (((size_t)(b << 8) + (uq << 6)) << 8) + dp;
#pragma unroll 4
        for (int ee = 0; ee < 64; ++ee) {
            float2 x = unpack_f16(ep[(size_t)ee << 8]);
            float4 w = *(const float4*)&wT[(uq << 6) + ee][0];   // wave-uniform
            p0x = fmaf(w.x, x.x, p0x); p0y = fmaf(w.x, x.y, p0y);
            p1x = fmaf(w.y, x.x, p1x); p1y = fmaf(w.y, x.y, p1y);
            p2x = fmaf(w.z, x.x, p2x); p2y = fmaf(w.z, x.y, p2y);
            p3x = fmaf(w.w, x.x, p3x); p3y = fmaf(w.w, x.y, p3y);
        }
        float2* sc = (float2*)smem;              // [16][256] float2 = 32 KB
        sc[((uq << 2) + 0) * 256 + dp] = make_float2(p0x, p0y);
        sc[((uq << 2) + 1) * 256 + dp] = make_float2(p1x, p1y);
        sc[((uq << 2) + 2) * 256 + dp] = make_float2(p2x, p2y);
        sc[((uq << 2) + 3) * 256 + dp] = make_float2(p3x, p3y);
        __syncthreads();
        const int q = tid >> 8;                  // 0..3
        float2 s0 = sc[(0 + q) * 256 + dp];
        float2 s1 = sc[(4 + q) * 256 + dp];
        float2 s2 = sc[(8 + q) * 256 + dp];
        float2 s3 = sc[(12 + q) * 256 + dp];
        float2 o = make_float2(s0.x + s1.x + s2.x + s3.x,
                               s0.y + s1.y + s2.y + s3.y);
        *(float2*)&out[(size_t)((b << 7) + q0 + q) * 512 + (dp << 1)] = o;
    }
}

// ---------------------------------------------------------------------------
extern "C" void kernel_launch(void* const* d_in, const int* in_sizes, int n_in,
                              void* d_out, int out_size, void* d_ws, size_t ws_size,
                              hipStream_t stream) {
    const float* enc      = (const float*)d_in[0];
    const float* dec      = (const float*)d_in[1];
    const float* Wenc     = (const float*)d_in[2];
    const float* Wdec     = (const float*)d_in[3];
    const float* Wscore   = (const float*)d_in[4];
    const float* bias_enc = (const float*)d_in[5];
    const float* bias_dec = (const float*)d_in[6];
    // d_in[7] = bias_score: constant shift, cancelled by softmax.
    float* out = (float*)d_out;

    float* ws = (float*)d_ws;
    unsigned short* EH  = (unsigned short*)ws;             // 2 MB  (1M fp16)
    float* Gq4          = ws + 524288;                     // 2 MB  (512K fp32)
    unsigned short* WeT = (unsigned short*)(ws + 1048576); // 512 KB
    unsigned short* WdT = WeT + 262144;                    // 512 KB
    unsigned short* enc16 = WdT + 262144;                  // 2 MB
    unsigned short* dec16 = enc16 + 1048576;               // 1 MB   (total 8 MB)

    prep_w<<<224, 256, 0, stream>>>(Wenc, Wdec, enc, dec, WeT, WdT, enc16, dec16);
    proj_kernel<<<768, 128, 0, stream>>>(enc16, dec16, WeT, WdT,
                                         bias_enc, bias_dec, EH, Gq4);
    attend_kernel<<<256, 1024, 0, stream>>>(enc16, EH, Gq4, Wscore, out);
}

// Round 14
// 111.654 us; speedup vs baseline: 1.0861x; 1.0243x over previous
//
#include <hip/hip_runtime.h>
#include <hip/hip_fp16.h>

typedef __attribute__((ext_vector_type(8))) _Float16 f16x8;
typedef __attribute__((ext_vector_type(4))) float f32x4;
typedef __attribute__((ext_vector_type(2))) __fp16 fp16x2;

__device__ inline unsigned int pack_f16(float x, float y) {
    union { fp16x2 h; unsigned int u; } c;
    c.h = __builtin_amdgcn_cvt_pkrtz(x, y);
    return c.u;
}
__device__ inline float2 unpack_f16(unsigned int u) {
    union { unsigned int u32; __half2 h2; } c; c.u32 = u;
    return __half22float2(c.h2);
}

// ---------------------------------------------------------------------------
// Kernel 0 (grid 224): bid<128: transpose+cvt W -> WT16[u][d] fp16.
//                      bid 128..191: enc fp32 -> fp16.  192..223: dec -> fp16.
// ---------------------------------------------------------------------------
__global__ __launch_bounds__(256) void prep_w(
    const float* __restrict__ Wenc, const float* __restrict__ Wdec,
    const float* __restrict__ enc,  const float* __restrict__ dec,
    unsigned short* __restrict__ WeT, unsigned short* __restrict__ WdT,
    unsigned short* __restrict__ enc16, unsigned short* __restrict__ dec16)
{
    __shared__ float L[64][65];
    const int bid = blockIdx.x;
    const int t = threadIdx.x;
    if (bid >= 128) {                    // fp32 -> fp16 bulk convert
        const float* src; unsigned int* dst;
        if (bid < 192) { int blk = bid - 128; src = enc + (size_t)blk * 16384;
                         dst = (unsigned int*)enc16 + (size_t)blk * 8192; }
        else           { int blk = bid - 192; src = dec + (size_t)blk * 16384;
                         dst = (unsigned int*)dec16 + (size_t)blk * 8192; }
#pragma unroll 4
        for (int i = 0; i < 16; ++i) {
            int off = (i << 10) + (t << 2);
            float4 v = *(const float4*)(src + off);
            *(uint2*)(dst + (off >> 1)) =
                make_uint2(pack_f16(v.x, v.y), pack_f16(v.z, v.w));
        }
        return;
    }
    const float* W = (bid < 64) ? Wenc : Wdec;
    unsigned short* T = (bid < 64) ? WeT : WdT;
    const int tb = bid & 63;
    const int d0 = (tb >> 3) << 6, u0v = (tb & 7) << 6;
    {
        const int c4 = (t & 15) << 2;
#pragma unroll
        for (int i = 0; i < 4; ++i) {
            int row = (i << 4) + (t >> 4);
            float4 v = *(const float4*)&W[(size_t)(d0 + row) * 512 + u0v + c4];
            L[row][c4 + 0] = v.x;
            L[row][c4 + 1] = v.y;
            L[row][c4 + 2] = v.z;
            L[row][c4 + 3] = v.w;
        }
    }
    __syncthreads();
    const int u = t >> 2, dg = t & 3;
    unsigned int hw[8];
#pragma unroll
    for (int j = 0; j < 8; ++j) {
        float x0 = L[(dg << 4) + (j << 1) + 0][u];
        float x1 = L[(dg << 4) + (j << 1) + 1][u];
        hw[j] = pack_f16(x0, x1);
    }
    size_t ob = (size_t)(u0v + u) * 512 + d0 + (dg << 4);
    *(uint4*)&T[ob]     = make_uint4(hw[0], hw[1], hw[2], hw[3]);
    *(uint4*)&T[ob + 8] = make_uint4(hw[4], hw[5], hw[6], hw[7]);
}

// ---------------------------------------------------------------------------
// Kernel 1 (grid 768, 256 thr = 4 waves): fp16 MFMA projections, K-SPLIT x2.
// Waves 0/1 = two 32x32 tile-halves over K[0,256); waves 2/3 same tiles over
// K[256,512). 3 blocks/CU = 3 waves/SIMD; dependent K-chain halved; partials
// reduced through padded LDS. 4-deep register pipeline, no spill under (256,3).
//   bid<512 : enc proj -> EH = exp2((d_enc+b)*2log2e) fp16, u-packed-by-4.
//   bid>=512: dec proj -> Gq4[b][q>>2][u][q&3] = exp2((dd+b)*2log2e) fp32.
// ---------------------------------------------------------------------------
__global__ __launch_bounds__(256, 3) void proj_kernel(
    const unsigned short* __restrict__ enc16, const unsigned short* __restrict__ dec16,
    const unsigned short* __restrict__ WeT,   const unsigned short* __restrict__ WdT,
    const float* __restrict__ bias_enc, const float* __restrict__ bias_dec,
    unsigned short* __restrict__ EH,   // [B][128][256][4] fp16
    float* __restrict__ Gq4)           // [B][32][512][4] fp32
{
    __shared__ float red[2][64][17];        // K-half-1 partials, pad 17 = no conflicts

    const float Cs = 2.8853900817779268f;   // 2*log2(e)
    const int bid = blockIdx.x;
    const int t = threadIdx.x;
    const int lane = t & 63, wv = t >> 6;
    const int th = wv & 1;                  // tile-half (32 rows)
    const int kh = wv >> 1;                 // K-half
    const int koff = kh << 8;               // 0 or 256
    const int frow = lane & 15, quad = lane >> 4;
    const int ko = quad << 3;

    const unsigned short *pa0, *pa1, *pb0, *pb1;
    if (bid < 512) {
        const int b = bid & 7, s = bid >> 3;
        const int u0 = ((s & 7) << 6) + (th << 5);   // 8 u-tiles of 64
        const int e0 = (s >> 3) << 5;                // 8 e-tiles of 32
        pa0 = WeT + (size_t)(u0 + frow) * 512 + ko + koff;
        pa1 = pa0 + 16 * 512;
        pb0 = enc16 + (size_t)((b << 8) + e0 + frow) * 512 + ko + koff;
        pb1 = pb0 + 16 * 512;
    } else {
        const int s = bid - 512;
        const int b = s & 7, s2 = s >> 3;
        const int q0 = ((s2 >> 4) << 6) + (th << 5); // 2 q-tiles of 64
        const int u0 = (s2 & 15) << 5;               // 16 u-tiles of 32
        pa0 = dec16 + (size_t)((b << 7) + q0 + frow) * 512 + ko + koff;
        pa1 = pa0 + 16 * 512;
        pb0 = WdT + (size_t)(u0 + frow) * 512 + ko + koff;
        pb1 = pb0 + 16 * 512;
    }

    f16x8 sa0[4], sa1[4], sb0[4], sb1[4];
    auto LD = [&](int st, int k) {
        sa0[st] = *(const f16x8*)(pa0 + k);
        sa1[st] = *(const f16x8*)(pa1 + k);
        sb0[st] = *(const f16x8*)(pb0 + k);
        sb1[st] = *(const f16x8*)(pb1 + k);
    };
    f32x4 acc[2][2] = {{{0.f,0.f,0.f,0.f},{0.f,0.f,0.f,0.f}},
                       {{0.f,0.f,0.f,0.f},{0.f,0.f,0.f,0.f}}};
    LD(0, 0); LD(1, 32); LD(2, 64); LD(3, 96);
    for (int k0 = 0; k0 < 256; k0 += 128) {
#pragma unroll
        for (int st = 0; st < 4; ++st) {
            acc[0][0] = __builtin_amdgcn_mfma_f32_16x16x32_f16(sa0[st], sb0[st], acc[0][0], 0, 0, 0);
            acc[0][1] = __builtin_amdgcn_mfma_f32_16x16x32_f16(sa0[st], sb1[st], acc[0][1], 0, 0, 0);
            acc[1][0] = __builtin_amdgcn_mfma_f32_16x16x32_f16(sa1[st], sb0[st], acc[1][0], 0, 0, 0);
            acc[1][1] = __builtin_amdgcn_mfma_f32_16x16x32_f16(sa1[st], sb1[st], acc[1][1], 0, 0, 0);
            LD(st, (k0 + 128 + (st << 5)) & 255);   // wrapped tail reload harmless
        }
    }

    // K-split reduction: waves 2,3 deposit partials; waves 0,1 add.
    if (kh == 1) {
#pragma unroll
        for (int fm = 0; fm < 2; ++fm)
#pragma unroll
            for (int fn = 0; fn < 2; ++fn)
#pragma unroll
                for (int g = 0; g < 4; ++g)
                    red[th][lane][(((fm << 1) + fn) << 2) + g] = acc[fm][fn][g];
    }
    __syncthreads();
    if (kh == 1) return;
#pragma unroll
    for (int fm = 0; fm < 2; ++fm)
#pragma unroll
        for (int fn = 0; fn < 2; ++fn)
#pragma unroll
            for (int g = 0; g < 4; ++g)
                acc[fm][fn][g] += red[th][lane][(((fm << 1) + fn) << 2) + g];

    // epilogue (C/D: col = lane&15 -> B-row, row = quad*4 + reg -> A-row)
    if (bid < 512) {
        const int b = bid & 7, s = bid >> 3;
        const int u0 = ((s & 7) << 6) + (th << 5);
        const int e0 = (s >> 3) << 5;
#pragma unroll
        for (int fm = 0; fm < 2; ++fm)
#pragma unroll
            for (int fn = 0; fn < 2; ++fn) {
                int ub = u0 + (fm << 4) + (quad << 2);
                int e  = e0 + (fn << 4) + frow;
                float4 bi = *(const float4*)&bias_enc[ub];
                float E0 = __builtin_amdgcn_exp2f((acc[fm][fn][0] + bi.x) * Cs);
                float E1 = __builtin_amdgcn_exp2f((acc[fm][fn][1] + bi.y) * Cs);
                float E2 = __builtin_amdgcn_exp2f((acc[fm][fn][2] + bi.z) * Cs);
                float E3 = __builtin_amdgcn_exp2f((acc[fm][fn][3] + bi.w) * Cs);
                ((uint2*)EH)[(((size_t)(b << 7) + (ub >> 2)) << 8) + e] =
                    make_uint2(pack_f16(E0, E1), pack_f16(E2, E3));
            }
    } else {
        const int s = bid - 512;
        const int b = s & 7, s2 = s >> 3;
        const int q0 = ((s2 >> 4) << 6) + (th << 5);
        const int u0 = (s2 & 15) << 5;
#pragma unroll
        for (int fm = 0; fm < 2; ++fm)
#pragma unroll
            for (int fn = 0; fn < 2; ++fn) {
                int qb = q0 + (fm << 4) + (quad << 2);   // multiple of 4
                int u  = u0 + (fn << 4) + frow;
                float bi = bias_dec[u];
                float G0 = __builtin_amdgcn_exp2f((acc[fm][fn][0] + bi) * Cs);
                float G1 = __builtin_amdgcn_exp2f((acc[fm][fn][1] + bi) * Cs);
                float G2 = __builtin_amdgcn_exp2f((acc[fm][fn][2] + bi) * Cs);
                float G3 = __builtin_amdgcn_exp2f((acc[fm][fn][3] + bi) * Cs);
                size_t base = (((size_t)(b << 5) + (qb >> 2)) << 11) + ((size_t)u << 2);
                *(float4*)&Gq4[base] = make_float4(G0, G1, G2, G3);
            }
    }
}

// ---------------------------------------------------------------------------
// Kernel 2 (grid 256, 1024 thr, q=4/block): scores -> softmax -> context.
// EXACT R11 version (best measured): E fp16 8B vector load 2-deep double
// buffer; G (q-packed, 64B) + Wscore via readfirstlane-pinned scalar loads,
// 1 group ahead. s = rcp(1 + E*G); logits = -2*sum (consts cancel).
// ---------------------------------------------------------------------------
__global__ __launch_bounds__(1024, 4) void attend_kernel(
    const unsigned short* __restrict__ enc16,  // [B,256,512] fp16
    const unsigned short* __restrict__ EH,     // [B][128][256][4] fp16
    const float* __restrict__ Gq4,             // [B][32][512][4] fp32
    const float* __restrict__ Wscore,          // [512]
    float* __restrict__ out)                   // [B, 128, 512]
{
    __shared__ float smem[8192];         // score accs 16 KB / ctx partials 32 KB
    __shared__ float wT[256][4];         // softmax weights [e][q]

    const float LOG2E = 1.4426950408889634f;

    const int bid = blockIdx.x;
    const int b = bid & 7;               // XCD-local batch
    const int qt = (bid >> 3) & 31;
    const int q0 = qt << 2;
    const int tid = threadIdx.x;
    const int wv = tid >> 6, lane = tid & 63;

    // ---------------- scores ----------------
    const int e  = ((wv & 3) << 6) + lane;
    const int uq = wv >> 2;
    const int u0 = __builtin_amdgcn_readfirstlane(uq << 7);   // SGPR-pinned

    const uint2* Ep = (const uint2*)EH + (((size_t)(b << 7) + (u0 >> 2)) << 8) + e;
    const float* Gq = Gq4 + (((size_t)(b << 5) + qt) << 11);  // [512][4]
    const float* Wp = Wscore + u0;

    float a0 = 0.f, a1 = 0.f, a2 = 0.f, a3 = 0.f;
    uint2 deA = Ep[0];
    uint2 deB = Ep[1 << 8];
    float4 g0 = *(const float4*)(Gq + ((u0 + 0) << 2));
    float4 g1 = *(const float4*)(Gq + ((u0 + 1) << 2));
    float4 g2 = *(const float4*)(Gq + ((u0 + 2) << 2));
    float4 g3 = *(const float4*)(Gq + ((u0 + 3) << 2));
    float4 w4 = *(const float4*)(Wp);

    auto PROC = [&](uint2 cde, float4 cg0, float4 cg1, float4 cg2, float4 cg3,
                    float4 cw) {
        float2 f01 = unpack_f16(cde.x);
        float2 f23 = unpack_f16(cde.y);
        float E;
        E = f01.x;
        a0 = fmaf(cw.x, __builtin_amdgcn_rcpf(fmaf(E, cg0.x, 1.f)), a0);
        a1 = fmaf(cw.x, __builtin_amdgcn_rcpf(fmaf(E, cg0.y, 1.f)), a1);
        a2 = fmaf(cw.x, __builtin_amdgcn_rcpf(fmaf(E, cg0.z, 1.f)), a2);
        a3 = fmaf(cw.x, __builtin_amdgcn_rcpf(fmaf(E, cg0.w, 1.f)), a3);
        E = f01.y;
        a0 = fmaf(cw.y, __builtin_amdgcn_rcpf(fmaf(E, cg1.x, 1.f)), a0);
        a1 = fmaf(cw.y, __builtin_amdgcn_rcpf(fmaf(E, cg1.y, 1.f)), a1);
        a2 = fmaf(cw.y, __builtin_amdgcn_rcpf(fmaf(E, cg1.z, 1.f)), a2);
        a3 = fmaf(cw.y, __builtin_amdgcn_rcpf(fmaf(E, cg1.w, 1.f)), a3);
        E = f23.x;
        a0 = fmaf(cw.z, __builtin_amdgcn_rcpf(fmaf(E, cg2.x, 1.f)), a0);
        a1 = fmaf(cw.z, __builtin_amdgcn_rcpf(fmaf(E, cg2.y, 1.f)), a1);
        a2 = fmaf(cw.z, __builtin_amdgcn_rcpf(fmaf(E, cg2.z, 1.f)), a2);
        a3 = fmaf(cw.z, __builtin_amdgcn_rcpf(fmaf(E, cg2.w, 1.f)), a3);
        E = f23.y;
        a0 = fmaf(cw.w, __builtin_amdgcn_rcpf(fmaf(E, cg3.x, 1.f)), a0);
        a1 = fmaf(cw.w, __builtin_amdgcn_rcpf(fmaf(E, cg3.y, 1.f)), a1);
        a2 = fmaf(cw.w, __builtin_amdgcn_rcpf(fmaf(E, cg3.z, 1.f)), a2);
        a3 = fmaf(cw.w, __builtin_amdgcn_rcpf(fmaf(E, cg3.w, 1.f)), a3);
    };

    for (int g = 0; g < 32; g += 2) {
        // even group g: E from deA, G/w current
        uint2 cde = deA;
        float4 cg0 = g0, cg1 = g1, cg2 = g2, cg3 = g3, cw = w4;
        deA = Ep[(size_t)((g + 2) & 31) << 8];
        {   // load G/w for group g+1
            int un = u0 + ((g + 1) << 2);
            g0 = *(const float4*)(Gq + ((un + 0) << 2));
            g1 = *(const float4*)(Gq + ((un + 1) << 2));
            g2 = *(const float4*)(Gq + ((un + 2) << 2));
            g3 = *(const float4*)(Gq + ((un + 3) << 2));
            w4 = *(const float4*)(Wp + ((g + 1) << 2));
        }
        PROC(cde, cg0, cg1, cg2, cg3, cw);

        // odd group g+1: E from deB, G/w current
        cde = deB;
        cg0 = g0; cg1 = g1; cg2 = g2; cg3 = g3; cw = w4;
        deB = Ep[(size_t)((g + 3) & 31) << 8];
        if (g < 30) {   // load G/w for group g+2
            int un = u0 + ((g + 2) << 2);
            g0 = *(const float4*)(Gq + ((un + 0) << 2));
            g1 = *(const float4*)(Gq + ((un + 1) << 2));
            g2 = *(const float4*)(Gq + ((un + 2) << 2));
            g3 = *(const float4*)(Gq + ((un + 3) << 2));
            w4 = *(const float4*)(Wp + ((g + 2) << 2));
        }
        PROC(cde, cg0, cg1, cg2, cg3, cw);
    }
    smem[((uq << 2) + 0) * 256 + e] = a0;
    smem[((uq << 2) + 1) * 256 + e] = a1;
    smem[((uq << 2) + 2) * 256 + e] = a2;
    smem[((uq << 2) + 3) * 256 + e] = a3;
    __syncthreads();

    // ---------------- softmax over e per q ----------------
    if (wv < 4) {
        const int q = wv;
        float l[4];
        float m = -1e30f;
#pragma unroll
        for (int i = 0; i < 4; ++i) {
            int ee = lane + (i << 6);
            float a = smem[(0 + q) * 256 + ee] + smem[(4 + q) * 256 + ee] +
                      smem[(8 + q) * 256 + ee] + smem[(12 + q) * 256 + ee];
            l[i] = -2.f * a;
            m = fmaxf(m, l[i]);
        }
#pragma unroll
        for (int mk = 32; mk >= 1; mk >>= 1) m = fmaxf(m, __shfl_xor(m, mk, 64));
        float p[4];
        float ssum = 0.f;
#pragma unroll
        for (int i = 0; i < 4; ++i) {
            p[i] = __builtin_amdgcn_exp2f((l[i] - m) * LOG2E);
            ssum += p[i];
        }
#pragma unroll
        for (int mk = 32; mk >= 1; mk >>= 1) ssum += __shfl_xor(ssum, mk, 64);
        float inv = __builtin_amdgcn_rcpf(ssum);
#pragma unroll
        for (int i = 0; i < 4; ++i) wT[lane + (i << 6)][q] = p[i] * inv;
    }
    __syncthreads();

    // ---------------- context (fp16 enc, 1x read, LDS reduce) ----------------
    {
        const int dp = tid & 255;                // d-pair index
        float p0x = 0.f, p0y = 0.f, p1x = 0.f, p1y = 0.f;
        float p2x = 0.f, p2y = 0.f, p3x = 0.f, p3y = 0.f;
        const unsigned int* ep = (const unsigned int*)enc16 +
                                 (((size_t)(b << 8) + (uq << 6)) << 8) + dp;
#pragma unroll 4
        for (int ee = 0; ee < 64; ++ee) {
            float2 x = unpack_f16(ep[(size_t)ee << 8]);
            float4 w = *(const float4*)&wT[(uq << 6) + ee][0];   // wave-uniform
            p0x = fmaf(w.x, x.x, p0x); p0y = fmaf(w.x, x.y, p0y);
            p1x = fmaf(w.y, x.x, p1x); p1y = fmaf(w.y, x.y, p1y);
            p2x = fmaf(w.z, x.x, p2x); p2y = fmaf(w.z, x.y, p2y);
            p3x = fmaf(w.w, x.x, p3x); p3y = fmaf(w.w, x.y, p3y);
        }
        float2* sc = (float2*)smem;              // [16][256] float2 = 32 KB
        sc[((uq << 2) + 0) * 256 + dp] = make_float2(p0x, p0y);
        sc[((uq << 2) + 1) * 256 + dp] = make_float2(p1x, p1y);
        sc[((uq << 2) + 2) * 256 + dp] = make_float2(p2x, p2y);
        sc[((uq << 2) + 3) * 256 + dp] = make_float2(p3x, p3y);
        __syncthreads();
        const int q = tid >> 8;                  // 0..3
        float2 s0 = sc[(0 + q) * 256 + dp];
        float2 s1 = sc[(4 + q) * 256 + dp];
        float2 s2 = sc[(8 + q) * 256 + dp];
        float2 s3 = sc[(12 + q) * 256 + dp];
        float2 o = make_float2(s0.x + s1.x + s2.x + s3.x,
                               s0.y + s1.y + s2.y + s3.y);
        *(float2*)&out[(size_t)((b << 7) + q0 + q) * 512 + (dp << 1)] = o;
    }
}

// ---------------------------------------------------------------------------
extern "C" void kernel_launch(void* const* d_in, const int* in_sizes, int n_in,
                              void* d_out, int out_size, void* d_ws, size_t ws_size,
                              hipStream_t stream) {
    const float* enc      = (const float*)d_in[0];
    const float* dec      = (const float*)d_in[1];
    const float* Wenc     = (const float*)d_in[2];
    const float* Wdec     = (const float*)d_in[3];
    const float* Wscore   = (const float*)d_in[4];
    const float* bias_enc = (const float*)d_in[5];
    const float* bias_dec = (const float*)d_in[6];
    // d_in[7] = bias_score: constant shift, cancelled by softmax.
    float* out = (float*)d_out;

    float* ws = (float*)d_ws;
    unsigned short* EH  = (unsigned short*)ws;             // 2 MB  (1M fp16)
    float* Gq4          = ws + 524288;                     // 2 MB  (512K fp32)
    unsigned short* WeT = (unsigned short*)(ws + 1048576); // 512 KB
    unsigned short* WdT = WeT + 262144;                    // 512 KB
    unsigned short* enc16 = WdT + 262144;                  // 2 MB
    unsigned short* dec16 = enc16 + 1048576;               // 1 MB   (total 8 MB)

    prep_w<<<224, 256, 0, stream>>>(Wenc, Wdec, enc, dec, WeT, WdT, enc16, dec16);
    proj_kernel<<<768, 256, 0, stream>>>(enc16, dec16, WeT, WdT,
                                         bias_enc, bias_dec, EH, Gq4);
    attend_kernel<<<256, 1024, 0, stream>>>(enc16, EH, Gq4, Wscore, out);
}